// Round 4
// baseline (128.231 us; speedup 1.0000x reference)
//
#include <hip/hip_runtime.h>

// Problem: B=8, C=6, H=W=1024, f32.
// loss = mean_b( sum_{pixels p: argmax_c tgt[b,:,p] != 0} var_unbiased_c(inp[b,:,p])
//                / (#distinct nonzero argmax labels in b + 1e-8) )
//
// R3: channel-streaming restructure. Running per-pixel accumulators (s, ss,
// best, arg) over a sequential channel loop -> only 1-2 streams hot at a time,
// 2KB contiguous bursts per wave per plane touch, 8 px/thread, single pass,
// 4096 blocks for full TLP.

#define BB 8
#define CC 6
#define HW (1024 * 1024)
#define F4 (HW / 4)              // float4 per channel plane = 262144
#define TPB 256
#define BLKS_PER_B 512           // 512 blocks * 256 thr * 8 px = 1M px per batch

using f4 = __attribute__((ext_vector_type(4))) float;

__global__ __launch_bounds__(64) void lv_init(float* ws_sum, unsigned int* ws_mask) {
    int t = threadIdx.x;
    if (t < BB) { ws_sum[t] = 0.0f; ws_mask[t] = 0u; }
}

__global__ __launch_bounds__(TPB) void lv_main(const float* __restrict__ inp,
                                               const float* __restrict__ tgt,
                                               float* __restrict__ ws_sum,
                                               unsigned int* __restrict__ ws_mask) {
    const int b = blockIdx.x >> 9;         // BLKS_PER_B = 512
    const int j = blockIdx.x & 511;

    const f4* ip4 = reinterpret_cast<const f4*>(inp) + (size_t)b * CC * F4;
    const f4* tp4 = reinterpret_cast<const f4*>(tgt) + (size_t)b * CC * F4;

    // each thread: 2 consecutive float4 per plane (8 px, 32 B/plane)
    const int base = (j * TPB + (int)threadIdx.x) * 2;

    // ---- argmax over target channels (running) ----
    float best[8];
    int   arg[8];
    {
        f4 t0 = tp4[base], t1 = tp4[base + 1];
#pragma unroll
        for (int k = 0; k < 4; ++k) {
            best[k]     = t0[k]; arg[k]     = 0;
            best[4 + k] = t1[k]; arg[4 + k] = 0;
        }
    }
#pragma unroll
    for (int c = 1; c < CC; ++c) {
        f4 t0 = tp4[(size_t)c * F4 + base], t1 = tp4[(size_t)c * F4 + base + 1];
#pragma unroll
        for (int k = 0; k < 4; ++k) {
            if (t0[k] > best[k])     { best[k] = t0[k];     arg[k] = c; }
            if (t1[k] > best[4 + k]) { best[4 + k] = t1[k]; arg[4 + k] = c; }
        }
    }

    // ---- sum / sumsq over input channels (running) ----
    float s[8] = {0, 0, 0, 0, 0, 0, 0, 0};
    float ss[8] = {0, 0, 0, 0, 0, 0, 0, 0};
#pragma unroll
    for (int c = 0; c < CC; ++c) {
        f4 a0 = ip4[(size_t)c * F4 + base], a1 = ip4[(size_t)c * F4 + base + 1];
#pragma unroll
        for (int k = 0; k < 4; ++k) {
            s[k] += a0[k];      ss[k]     = fmaf(a0[k], a0[k], ss[k]);
            s[4 + k] += a1[k];  ss[4 + k] = fmaf(a1[k], a1[k], ss[4 + k]);
        }
    }

    // ---- per-pixel epilogue ----
    float sum_local = 0.0f;
    unsigned int mask_local = 0u;
#pragma unroll
    for (int k = 0; k < 8; ++k) {
        if (arg[k] != 0) {
            float var = (ss[k] - s[k] * s[k] * (1.0f / CC)) * (1.0f / (CC - 1));
            sum_local += var;
            mask_local |= (1u << arg[k]);
        }
    }

    // wave-level reduce (64 lanes)
#pragma unroll
    for (int off = 32; off >= 1; off >>= 1) {
        sum_local  += __shfl_xor(sum_local, off, 64);
        mask_local |= (unsigned int)__shfl_xor((int)mask_local, off, 64);
    }

    // cross-wave reduce via LDS (4 waves)
    __shared__ float s_sum[4];
    __shared__ unsigned int s_mask[4];
    const int lane = threadIdx.x & 63;
    const int wid  = threadIdx.x >> 6;
    if (lane == 0) { s_sum[wid] = sum_local; s_mask[wid] = mask_local; }
    __syncthreads();
    if (threadIdx.x == 0) {
        float bs = s_sum[0] + s_sum[1] + s_sum[2] + s_sum[3];
        unsigned int bm = s_mask[0] | s_mask[1] | s_mask[2] | s_mask[3];
        atomicAdd(&ws_sum[b], bs);
        atomicOr(&ws_mask[b], bm);
    }
}

__global__ __launch_bounds__(64) void lv_final(const float* __restrict__ ws_sum,
                                               const unsigned int* __restrict__ ws_mask,
                                               float* __restrict__ out) {
    if (threadIdx.x == 0) {
        float acc = 0.0f;
        for (int b = 0; b < BB; ++b) {
            // bits 1..5 = nonzero labels present
            float n = (float)__popc(ws_mask[b] & 0x3Eu);
            acc += ws_sum[b] / (n + 1e-8f);
        }
        out[0] = acc * (1.0f / BB);
    }
}

extern "C" void kernel_launch(void* const* d_in, const int* in_sizes, int n_in,
                              void* d_out, int out_size, void* d_ws, size_t ws_size,
                              hipStream_t stream) {
    const float* inp = (const float*)d_in[0];
    const float* tgt = (const float*)d_in[1];
    float* out = (float*)d_out;

    float* ws_sum = (float*)d_ws;                          // 8 floats
    unsigned int* ws_mask = (unsigned int*)(ws_sum + BB);  // 8 uints

    lv_init<<<1, 64, 0, stream>>>(ws_sum, ws_mask);
    lv_main<<<BB * BLKS_PER_B, TPB, 0, stream>>>(inp, tgt, ws_sum, ws_mask);
    lv_final<<<1, 64, 0, stream>>>(ws_sum, ws_mask, out);
}

// Round 5
// 85.203 us; speedup vs baseline: 1.5050x; 1.5050x over previous
//
#include <hip/hip_runtime.h>

// Problem: B=8, C=6, H=W=1024, f32.
// loss = mean_b( sum_{pixels p: argmax_c tgt[b,:,p] != 0} var_unbiased_c(inp[b,:,p])
//                / (#distinct nonzero argmax labels in b + 1e-8) )
//
// R0-R2: three schedules, all ~90us, delivery pinned at 4.46 TB/s, FETCH=201MB
// (50% L3 hit) -> shared-resource ceiling. R3 stride-2 coalescing bug: reverted.
// R4: single change vs R2 -- NON-TEMPORAL loads on target so it never allocates
// in L2/L3; input (201MB) then fits fully resident in L3 (256MB) across replays.
// Target streams from HBM in parallel with input L3 hits.

#define BB 8
#define CC 6
#define HW (1024 * 1024)
#define F4 (HW / 4)              // float4 elements per channel plane = 262144
#define TPB 256
#define BLOCKS_PER_B 256         // 256 blocks * 256 thr * 4 iters * 4 px = 1M pixels
#define ITERS 4                  // (F4 / TPB) / BLOCKS_PER_B

using f4 = __attribute__((ext_vector_type(4))) float;

__global__ __launch_bounds__(64) void lv_init(float* ws_sum, unsigned int* ws_mask) {
    int t = threadIdx.x;
    if (t < BB) { ws_sum[t] = 0.0f; ws_mask[t] = 0u; }
}

__global__ __launch_bounds__(TPB, 2) void lv_main(const float* __restrict__ inp,
                                                  const float* __restrict__ tgt,
                                                  float* __restrict__ ws_sum,
                                                  unsigned int* __restrict__ ws_mask) {
    const int b  = blockIdx.x >> 8;        // BLOCKS_PER_B = 256
    const int jb = blockIdx.x & 255;

    const f4* ip4 = reinterpret_cast<const f4*>(inp) + (size_t)b * CC * F4;
    const f4* tp4 = reinterpret_cast<const f4*>(tgt) + (size_t)b * CC * F4;

    float sum_local = 0.0f;
    unsigned int mask_local = 0u;

    // double-buffered register prefetch; indices all compile-time (rule #20)
    f4 bi[2][CC], bt[2][CC];

    {   // prologue: load iteration 0
        const int f4i = jb * TPB + (int)threadIdx.x;
#pragma unroll
        for (int c = 0; c < CC; ++c) {
            bi[0][c] = ip4[(size_t)c * F4 + f4i];
            bt[0][c] = __builtin_nontemporal_load(&tp4[(size_t)c * F4 + f4i]);
        }
    }

#pragma unroll
    for (int it = 0; it < ITERS; ++it) {
        const int cur = it & 1;
        const int nxt = cur ^ 1;

        // prefetch next iteration's 12 float4 BEFORE consuming current
        if (it + 1 < ITERS) {
            const int f4i = ((it + 1) * BLOCKS_PER_B + jb) * TPB + (int)threadIdx.x;
#pragma unroll
            for (int c = 0; c < CC; ++c) {
                bi[nxt][c] = ip4[(size_t)c * F4 + f4i];
                bt[nxt][c] = __builtin_nontemporal_load(&tp4[(size_t)c * F4 + f4i]);
            }
        }

        // pin: scheduler may NOT sink the loads above below this point,
        // nor hoist the consume phase above it.
        __builtin_amdgcn_sched_barrier(0);

        // consume current buffer
#pragma unroll
        for (int k = 0; k < 4; ++k) {
            float s = 0.0f, ss = 0.0f;
#pragma unroll
            for (int c = 0; c < CC; ++c) {
                float v = bi[cur][c][k];
                s += v;
                ss = fmaf(v, v, ss);
            }
            float best = bt[cur][0][k];
            int arg = 0;
#pragma unroll
            for (int c = 1; c < CC; ++c) {
                float t = bt[cur][c][k];
                if (t > best) { best = t; arg = c; }   // strict >: first-occurrence argmax
            }
            if (arg != 0) {
                // unbiased variance over C=6 channels (ddof=1)
                float var = (ss - s * s * (1.0f / CC)) * (1.0f / (CC - 1));
                sum_local += var;
                mask_local |= (1u << arg);
            }
        }

        __builtin_amdgcn_sched_barrier(0);
    }

    // wave-level reduce (64 lanes)
#pragma unroll
    for (int off = 32; off >= 1; off >>= 1) {
        sum_local  += __shfl_xor(sum_local, off, 64);
        mask_local |= (unsigned int)__shfl_xor((int)mask_local, off, 64);
    }

    // cross-wave reduce via LDS (4 waves)
    __shared__ float s_sum[4];
    __shared__ unsigned int s_mask[4];
    const int lane = threadIdx.x & 63;
    const int wid  = threadIdx.x >> 6;
    if (lane == 0) { s_sum[wid] = sum_local; s_mask[wid] = mask_local; }
    __syncthreads();
    if (threadIdx.x == 0) {
        float bs = s_sum[0] + s_sum[1] + s_sum[2] + s_sum[3];
        unsigned int bm = s_mask[0] | s_mask[1] | s_mask[2] | s_mask[3];
        atomicAdd(&ws_sum[b], bs);
        atomicOr(&ws_mask[b], bm);
    }
}

__global__ __launch_bounds__(64) void lv_final(const float* __restrict__ ws_sum,
                                               const unsigned int* __restrict__ ws_mask,
                                               float* __restrict__ out) {
    if (threadIdx.x == 0) {
        float acc = 0.0f;
        for (int b = 0; b < BB; ++b) {
            // bits 1..5 = nonzero labels present
            float n = (float)__popc(ws_mask[b] & 0x3Eu);
            acc += ws_sum[b] / (n + 1e-8f);
        }
        out[0] = acc * (1.0f / BB);
    }
}

extern "C" void kernel_launch(void* const* d_in, const int* in_sizes, int n_in,
                              void* d_out, int out_size, void* d_ws, size_t ws_size,
                              hipStream_t stream) {
    const float* inp = (const float*)d_in[0];
    const float* tgt = (const float*)d_in[1];
    float* out = (float*)d_out;

    float* ws_sum = (float*)d_ws;                          // 8 floats
    unsigned int* ws_mask = (unsigned int*)(ws_sum + BB);  // 8 uints

    lv_init<<<1, 64, 0, stream>>>(ws_sum, ws_mask);
    lv_main<<<BB * BLOCKS_PER_B, TPB, 0, stream>>>(inp, tgt, ws_sum, ws_mask);
    lv_final<<<1, 64, 0, stream>>>(ws_sum, ws_mask, out);
}